// Round 1
// baseline (2352.144 us; speedup 1.0000x reference)
//
#include <hip/hip_runtime.h>

constexpr int BLK = 256;
constexpr int HD  = 32;   // hidden size

// ---------------- fast activations (NaN-safe at +/-inf) ----------------
__device__ __forceinline__ float sigmoid_f(float x) {
    // 1/(1+e^-x); x<<0 -> exp=inf -> 0 ; x>>0 -> exp=0 -> 1
    return __fdividef(1.0f, 1.0f + __expf(-x));
}
__device__ __forceinline__ float tanh_f(float x) {
    // 1 - 2/(e^{2x}+1); x>>0 -> 1 ; x<<0 -> -1  (no inf/inf NaN)
    return 1.0f - __fdividef(2.0f, __expf(2.0f * x) + 1.0f);
}

// ---------------- precompute folded weights into d_ws ----------------
// ws layout (floats):
//   [0    .. 4095] WcT[128][32]   : WcT[g][k] = W_hh[g][k] + W_hp[0][k]*W0[0][g] + W_hp[1][k]*W0[1][g]
//   [4096 .. 4223] bg2[128]       : steady-state gate bias
//   [4224 .. 4351] bias0[128]     : step-0 gate bias (w/o lp terms)
//   [4352 .. 4479] W00[128]       : W0[0][g] = sum_e W_se[e][0]*W_ih[g][e]
//   [4480 .. 4607] W01[128]       : W0[1][g]
__global__ void precompute_kernel(const float* __restrict__ W_se,
                                  const float* __restrict__ b_se,
                                  const float* __restrict__ W_ih,
                                  const float* __restrict__ b_ih,
                                  const float* __restrict__ W_hh,
                                  const float* __restrict__ b_hh,
                                  const float* __restrict__ W_hp,
                                  const float* __restrict__ b_hp,
                                  float* __restrict__ ws) {
    int g = threadIdx.x;             // 0..127
    if (g >= 128) return;
    float w0 = 0.f, w1 = 0.f, bse = 0.f;
    for (int e = 0; e < 32; ++e) {
        float wi = W_ih[g * 32 + e];
        w0  += W_se[e * 2 + 0] * wi;   // W_se is (E=32, O=2) row-major
        w1  += W_se[e * 2 + 1] * wi;
        bse += b_se[e] * wi;
    }
    float bg = b_ih[g] + b_hh[g];
    for (int k = 0; k < 32; ++k) {
        // W_hp is (2,32) row-major: W_hp[o][k] = W_hp[o*32+k]
        ws[g * 32 + k] = W_hh[g * 32 + k] + W_hp[k] * w0 + W_hp[32 + k] * w1;
    }
    ws[4096 + g] = bg + bse + b_hp[0] * w0 + b_hp[1] * w1;  // bg2
    ws[4224 + g] = bg + bse;                                 // bias0
    ws[4352 + g] = w0;                                       // W0[0][g]
    ws[4480 + g] = w1;                                       // W0[1][g]
}

// ---------------- main LSTM kernel: one thread per agent ----------------
__global__ __launch_bounds__(BLK) void lstm_kernel(
        const float* __restrict__ last_pos_rel,   // (B,2)
        const float* __restrict__ hidden_state,   // (1,B,32)
        const float* __restrict__ start_pos,      // (B,2)
        const float* __restrict__ W_hh,           // (128,32) row-major (step 0)
        const float* __restrict__ W_hp,           // (2,32)
        const float* __restrict__ b_hp,           // (2)
        const float* __restrict__ ws,             // precomputed
        const int*   __restrict__ seq_len_p,
        float* __restrict__ out,                  // [T*B*2] traj then [B*32] hT
        int Bn) {
    __shared__ float h_lds[HD * BLK];
    __shared__ float c_lds[HD * BLK];

    const int tid = threadIdx.x;
    const int b   = blockIdx.x * BLK + tid;
    if (b >= Bn) return;
    const int T = seq_len_p[0];

    const float* __restrict__ WcT   = ws;
    const float* __restrict__ bg2   = ws + 4096;
    const float* __restrict__ bias0 = ws + 4224;
    const float* __restrict__ W00   = ws + 4352;
    const float* __restrict__ W01   = ws + 4480;

    // load h0
    float h[HD];
    {
        const float4* hp = reinterpret_cast<const float4*>(hidden_state + (size_t)b * HD);
        #pragma unroll
        for (int k = 0; k < HD / 4; ++k) {
            float4 v = hp[k];
            h[4*k+0] = v.x; h[4*k+1] = v.y; h[4*k+2] = v.z; h[4*k+3] = v.w;
        }
    }
    // c0 = 0
    #pragma unroll
    for (int j = 0; j < HD; ++j) c_lds[j * BLK + tid] = 0.f;

    const float2 lp  = reinterpret_cast<const float2*>(last_pos_rel)[b];
    float2 run       = reinterpret_cast<const float2*>(start_pos)[b];
    const float lp0 = lp.x, lp1 = lp.y;
    float run0 = run.x, run1 = run.y;

    #pragma unroll 1
    for (int t = 0; t < T; ++t) {
        const bool  first = (t == 0);
        const float* __restrict__ Wg = first ? W_hh : WcT;

        #pragma unroll 1
        for (int jc = 0; jc < HD / 4; ++jc) {
            #pragma unroll
            for (int m = 0; m < 4; ++m) {
                const int j = jc * 4 + m;
                float acc[4];
                #pragma unroll
                for (int gt = 0; gt < 4; ++gt) {
                    const int row = gt * 32 + j;          // i,f,g,o rows
                    float a = first ? (bias0[row] + lp0 * W00[row] + lp1 * W01[row])
                                    : bg2[row];
                    const float* __restrict__ wr = Wg + row * 32;
                    #pragma unroll
                    for (int k = 0; k < HD; ++k) a = fmaf(h[k], wr[k], a);
                    acc[gt] = a;
                }
                const float si = sigmoid_f(acc[0]);
                const float sf = sigmoid_f(acc[1]);
                const float tg = tanh_f(acc[2]);
                const float so = sigmoid_f(acc[3]);
                const float cold = c_lds[j * BLK + tid];
                const float cn   = fmaf(sf, cold, si * tg);
                c_lds[j * BLK + tid] = cn;
                h_lds[j * BLK + tid] = so * tanh_f(cn);
            }
        }
        // refresh h registers with h_{t+1}
        #pragma unroll
        for (int k = 0; k < HD; ++k) h[k] = h_lds[k * BLK + tid];

        // pos_rel = h @ W_hp^T + b_hp ; cumsum ; write
        float p0 = b_hp[0], p1 = b_hp[1];
        #pragma unroll
        for (int k = 0; k < HD; ++k) {
            p0 = fmaf(h[k], W_hp[k],      p0);
            p1 = fmaf(h[k], W_hp[32 + k], p1);
        }
        run0 += p0; run1 += p1;
        float2 w2; w2.x = run0; w2.y = run1;
        reinterpret_cast<float2*>(out)[(size_t)t * Bn + b] = w2;
    }

    // final hidden state
    float4* oh = reinterpret_cast<float4*>(out + (size_t)T * Bn * 2 + (size_t)b * HD);
    #pragma unroll
    for (int k = 0; k < HD / 4; ++k) {
        float4 v;
        v.x = h[4*k+0]; v.y = h[4*k+1]; v.z = h[4*k+2]; v.w = h[4*k+3];
        oh[k] = v;
    }
}

extern "C" void kernel_launch(void* const* d_in, const int* in_sizes, int n_in,
                              void* d_out, int out_size, void* d_ws, size_t ws_size,
                              hipStream_t stream) {
    const float* last_pos_rel = (const float*)d_in[0];
    const float* hidden_state = (const float*)d_in[1];
    const float* start_pos    = (const float*)d_in[2];
    const float* W_se         = (const float*)d_in[3];
    const float* b_se         = (const float*)d_in[4];
    const float* W_ih         = (const float*)d_in[5];
    const float* b_ih         = (const float*)d_in[6];
    const float* W_hh         = (const float*)d_in[7];
    const float* b_hh         = (const float*)d_in[8];
    const float* W_hp         = (const float*)d_in[9];
    const float* b_hp         = (const float*)d_in[10];
    const int*   seq_len      = (const int*)d_in[11];

    float* out = (float*)d_out;
    float* ws  = (float*)d_ws;

    const int Bn = in_sizes[0] / 2;   // last_pos_rel is (B,2)

    hipLaunchKernelGGL(precompute_kernel, dim3(1), dim3(128), 0, stream,
                       W_se, b_se, W_ih, b_ih, W_hh, b_hh, W_hp, b_hp, ws);

    const int nblocks = (Bn + BLK - 1) / BLK;
    hipLaunchKernelGGL(lstm_kernel, dim3(nblocks), dim3(BLK), 0, stream,
                       last_pos_rel, hidden_state, start_pos, W_hh, W_hp, b_hp,
                       ws, seq_len, out, Bn);
}

// Round 2
// 372.074 us; speedup vs baseline: 6.3217x; 6.3217x over previous
//
#include <hip/hip_runtime.h>

typedef _Float16 half8 __attribute__((ext_vector_type(8)));
typedef float f32x4 __attribute__((ext_vector_type(4)));

#define L2E 1.44269504088896340736f
#define MFMA(a, b, c) __builtin_amdgcn_mfma_f32_16x16x32_f16((a), (b), (c), 0, 0, 0)

// ws float layout:
//   0    : Wcs [128][32]  scaled folded recurrent weight
//   4096 : Whhs[128][32]  scaled W_hh (step 0)
//   8192 : W00s[128]      scaled lp0 rank-1 row
//   8320 : W01s[128]      scaled lp1 rank-1 row
//   8448 : bg2s[128]      scaled steady-state gate bias
//   8576 : b0s [128]      scaled step-0 gate bias
__global__ void precompute_kernel(const float* __restrict__ W_se,
                                  const float* __restrict__ b_se,
                                  const float* __restrict__ W_ih,
                                  const float* __restrict__ b_ih,
                                  const float* __restrict__ W_hh,
                                  const float* __restrict__ b_hh,
                                  const float* __restrict__ W_hp,
                                  const float* __restrict__ b_hp,
                                  float* __restrict__ ws) {
    int g = threadIdx.x;
    if (g >= 128) return;
    float w0 = 0.f, w1 = 0.f, bse = 0.f;
    for (int e = 0; e < 32; ++e) {
        float wi = W_ih[g * 32 + e];
        w0  += W_se[e * 2 + 0] * wi;
        w1  += W_se[e * 2 + 1] * wi;
        bse += b_se[e] * wi;
    }
    // gate row scaling: i,f,o rows * -log2(e)  (sigmoid via exp2)
    //                   g rows   * 2*log2(e)   (tanh via exp2)
    float s = ((g >> 5) == 2) ? 2.0f * L2E : -L2E;
    for (int k = 0; k < 32; ++k) {
        float whh = W_hh[g * 32 + k];
        ws[g * 32 + k]        = s * (whh + W_hp[k] * w0 + W_hp[32 + k] * w1);
        ws[4096 + g * 32 + k] = s * whh;
    }
    float bg = b_ih[g] + b_hh[g] + bse;
    ws[8192 + g] = s * w0;
    ws[8320 + g] = s * w1;
    ws[8448 + g] = s * (bg + b_hp[0] * w0 + b_hp[1] * w1);
    ws[8576 + g] = s * bg;
}

__device__ __forceinline__ void split8(const float v[8], half8& hi, half8& lo) {
    #pragma unroll
    for (int i = 0; i < 8; ++i) {
        _Float16 h = (_Float16)v[i];
        hi[i] = h;
        lo[i] = (_Float16)(v[i] - (float)h);
    }
}

// one wave (64 threads) per 16-agent tile
__global__ __launch_bounds__(64) void lstm_kernel(
        const float* __restrict__ lp,    // last_pos_rel (B,2)
        const float* __restrict__ h0g,   // hidden_state (1,B,32)
        const float* __restrict__ sp,    // start_pos (B,2)
        const float* __restrict__ Whp,   // (2,32)
        const float* __restrict__ bhp,   // (2)
        const float* __restrict__ ws,
        const int*   __restrict__ seqp,
        float* __restrict__ out, int Bn) {
    __shared__ float hlds[16 * 36];      // padded stride 36 floats

    const int l    = threadIdx.x;
    const int col  = l & 15;             // A-row / D-col role
    const int q    = l >> 4;
    const int base = blockIdx.x * 16;
    const int T    = seqp[0];

    const float* Wcs  = ws;
    const float* Whhs = ws + 4096;
    const float* W00s = ws + 8192;
    const float* W01s = ws + 8320;
    const float* bg2s = ws + 8448;
    const float* b0s  = ws + 8576;

    // per-lane steady-state gate bias (D[m][n]: bias depends on n=col only)
    float bg2r[8];
    #pragma unroll
    for (int t8 = 0; t8 < 8; ++t8) bg2r[t8] = bg2s[t8 * 16 + col];
    const float posb = (col < 2) ? bhp[col] : 0.f;

    // A0 fragment from h0: A[m=col][k=8q+i]
    half8 a0h, a0l;
    {
        float v[8];
        const float* p = h0g + (size_t)(base + col) * 32 + 8 * q;
        #pragma unroll
        for (int i = 0; i < 8; ++i) v[i] = p[i];
        split8(v, a0h, a0l);
    }
    // lp fragment: only k=0,1 nonzero (q==0 lanes)
    half8 aph, apl;
    #pragma unroll
    for (int i = 0; i < 8; ++i) { aph[i] = (_Float16)0.f; apl[i] = (_Float16)0.f; }
    if (q == 0) {
        float l0 = lp[(size_t)(base + col) * 2 + 0];
        float l1 = lp[(size_t)(base + col) * 2 + 1];
        _Float16 h0v = (_Float16)l0; aph[0] = h0v; apl[0] = (_Float16)(l0 - (float)h0v);
        _Float16 h1v = (_Float16)l1; aph[1] = h1v; apl[1] = (_Float16)(l1 - (float)h1v);
    }

    // ---- GEMM_0: gates_0 = h0*Whh^T + lp-terms + bias0 (all pre-scaled) ----
    f32x4 accg[8];
    #pragma unroll
    for (int t8 = 0; t8 < 8; ++t8) {
        f32x4 a;
        float b0v = b0s[t8 * 16 + col];
        a[0] = b0v; a[1] = b0v; a[2] = b0v; a[3] = b0v;
        half8 bh, bl;
        {
            float v[8];
            const float* p = Whhs + (size_t)(t8 * 16 + col) * 32 + 8 * q;
            #pragma unroll
            for (int i = 0; i < 8; ++i) v[i] = p[i];
            split8(v, bh, bl);
        }
        a = MFMA(a0h, bh, a); a = MFMA(a0l, bh, a);
        a = MFMA(a0h, bl, a); a = MFMA(a0l, bl, a);
        // lp * [W00;W01] rows (B[k=0]=W00 row, B[k=1]=W01 row)
        half8 b0h, b0l;
        #pragma unroll
        for (int i = 0; i < 8; ++i) { b0h[i] = (_Float16)0.f; b0l[i] = (_Float16)0.f; }
        if (q == 0) {
            float w0v = W00s[t8 * 16 + col];
            float w1v = W01s[t8 * 16 + col];
            _Float16 hh0 = (_Float16)w0v; b0h[0] = hh0; b0l[0] = (_Float16)(w0v - (float)hh0);
            _Float16 hh1 = (_Float16)w1v; b0h[1] = hh1; b0l[1] = (_Float16)(w1v - (float)hh1);
        }
        a = MFMA(aph, b0h, a); a = MFMA(apl, b0h, a);
        a = MFMA(aph, b0l, a); a = MFMA(apl, b0l, a);
        accg[t8] = a;
    }

    // ---- persistent B fragments: Wc (8 tiles) + Whp ----
    half8 wh[8], wl[8];
    #pragma unroll
    for (int t8 = 0; t8 < 8; ++t8) {
        float v[8];
        const float* p = Wcs + (size_t)(t8 * 16 + col) * 32 + 8 * q;
        #pragma unroll
        for (int i = 0; i < 8; ++i) v[i] = p[i];
        split8(v, wh[t8], wl[t8]);
    }
    half8 ph, plo;
    #pragma unroll
    for (int i = 0; i < 8; ++i) { ph[i] = (_Float16)0.f; plo[i] = (_Float16)0.f; }
    if (col < 2) {
        float v[8];
        const float* p = Whp + col * 32 + 8 * q;
        #pragma unroll
        for (int i = 0; i < 8; ++i) v[i] = p[i];
        split8(v, ph, plo);
    }

    // per-lane recurrent state: agents m = 4q+r, hidden j = col + 16d
    float c[8];
    #pragma unroll
    for (int i = 0; i < 8; ++i) c[i] = 0.f;
    float run[4] = {0.f, 0.f, 0.f, 0.f};
    if (col < 2) {
        #pragma unroll
        for (int r = 0; r < 4; ++r) run[r] = sp[(size_t)(base + 4 * q + r) * 2 + col];
    }

    float hn[8];
    #pragma unroll 1
    for (int n = 0; n < T; ++n) {
        // ---- activations: i,f,g,o for (m=4q+r, j=col+16d) all in-lane ----
        #pragma unroll
        for (int d = 0; d < 2; ++d) {
            #pragma unroll
            for (int r = 0; r < 4; ++r) {
                float gi = accg[0 + d][r];   // pre-scaled by -log2e
                float gf = accg[2 + d][r];
                float gg = accg[4 + d][r];   // pre-scaled by 2log2e
                float go = accg[6 + d][r];
                float ei = __builtin_amdgcn_exp2f(gi);   // e^{-i}
                float ef = __builtin_amdgcn_exp2f(gf);   // e^{-f}
                float eg = __builtin_amdgcn_exp2f(gg);   // e^{2g}
                float eo = __builtin_amdgcn_exp2f(go);   // e^{-o}
                float Di = 1.f + ei, Df = 1.f + ef, Dg = 1.f + eg, Do = 1.f + eo;
                // c' = c/Df + (eg-1)/(Di*Dg)  (combined denominator, 1 rcp)
                float P  = Di * Dg;
                float R  = __builtin_amdgcn_rcpf(P * Df);
                float cn = fmaf(eg - 1.f, Df, c[d * 4 + r] * P) * R;
                c[d * 4 + r] = cn;
                // h = (e^{2c}-1)/((1+e^{2c})*Do)
                float ec = __builtin_amdgcn_exp2f(cn * (2.f * L2E));
                float Rs = __builtin_amdgcn_rcpf((1.f + ec) * Do);
                hn[d * 4 + r] = (ec - 1.f) * Rs;
            }
        }
        // ---- stage h_{n+1} to LDS, rebuild A fragment ----
        #pragma unroll
        for (int d = 0; d < 2; ++d)
            #pragma unroll
            for (int r = 0; r < 4; ++r)
                hlds[(4 * q + r) * 36 + col + 16 * d] = hn[d * 4 + r];
        __syncthreads();
        float av[8];
        {
            const float4 x0 = *(const float4*)&hlds[col * 36 + 8 * q + 0];
            const float4 x1 = *(const float4*)&hlds[col * 36 + 8 * q + 4];
            av[0] = x0.x; av[1] = x0.y; av[2] = x0.z; av[3] = x0.w;
            av[4] = x1.x; av[5] = x1.y; av[6] = x1.z; av[7] = x1.w;
        }
        __syncthreads();
        half8 ah, al;
        split8(av, ah, al);

        // ---- pos_n = h_{n+1} * Whp^T + bhp ----
        f32x4 ap;
        ap[0] = posb; ap[1] = posb; ap[2] = posb; ap[3] = posb;
        ap = MFMA(ah, ph, ap); ap = MFMA(al, ph, ap);
        ap = MFMA(ah, plo, ap); ap = MFMA(al, plo, ap);

        // ---- gates_{n+1} = h_{n+1} * Wc^T + bg2 ----
        if (n + 1 < T) {
            #pragma unroll
            for (int t8 = 0; t8 < 8; ++t8) {
                f32x4 a;
                a[0] = bg2r[t8]; a[1] = bg2r[t8]; a[2] = bg2r[t8]; a[3] = bg2r[t8];
                a = MFMA(ah, wh[t8], a); a = MFMA(al, wh[t8], a);
                a = MFMA(ah, wl[t8], a); a = MFMA(al, wl[t8], a);
                accg[t8] = a;
            }
        }

        // ---- cumsum + store traj ----
        if (col < 2) {
            #pragma unroll
            for (int r = 0; r < 4; ++r) {
                run[r] += ap[r];
                out[((size_t)n * Bn + base + 4 * q + r) * 2 + col] = run[r];
            }
        }
    }

    // final hidden state hT = h_T
    #pragma unroll
    for (int d = 0; d < 2; ++d)
        #pragma unroll
        for (int r = 0; r < 4; ++r)
            out[(size_t)T * Bn * 2 + (size_t)(base + 4 * q + r) * 32 + col + 16 * d]
                = hn[d * 4 + r];
}

extern "C" void kernel_launch(void* const* d_in, const int* in_sizes, int n_in,
                              void* d_out, int out_size, void* d_ws, size_t ws_size,
                              hipStream_t stream) {
    const float* last_pos_rel = (const float*)d_in[0];
    const float* hidden_state = (const float*)d_in[1];
    const float* start_pos    = (const float*)d_in[2];
    const float* W_se         = (const float*)d_in[3];
    const float* b_se         = (const float*)d_in[4];
    const float* W_ih         = (const float*)d_in[5];
    const float* b_ih         = (const float*)d_in[6];
    const float* W_hh         = (const float*)d_in[7];
    const float* b_hh         = (const float*)d_in[8];
    const float* W_hp         = (const float*)d_in[9];
    const float* b_hp         = (const float*)d_in[10];
    const int*   seq_len      = (const int*)d_in[11];

    float* out = (float*)d_out;
    float* ws  = (float*)d_ws;

    const int Bn = in_sizes[0] / 2;

    hipLaunchKernelGGL(precompute_kernel, dim3(1), dim3(128), 0, stream,
                       W_se, b_se, W_ih, b_ih, W_hh, b_hh, W_hp, b_hp, ws);

    const int ntiles = (Bn + 15) / 16;
    hipLaunchKernelGGL(lstm_kernel, dim3(ntiles), dim3(64), 0, stream,
                       last_pos_rel, hidden_state, start_pos, W_hp, b_hp,
                       ws, seq_len, out, Bn);
}

// Round 3
// 313.252 us; speedup vs baseline: 7.5088x; 1.1878x over previous
//
#include <hip/hip_runtime.h>

typedef _Float16 half8 __attribute__((ext_vector_type(8)));
typedef float f32x4 __attribute__((ext_vector_type(4)));

#define L2E 1.44269504088896340736f
#define MFMA(a, b, c) __builtin_amdgcn_mfma_f32_16x16x32_f16((a), (b), (c), 0, 0, 0)

// Row-permuted + pre-scaled weights so that the D-fragment of gates^T = Wc·h^T
// lands i,f,g,o for (agent=col, j=8q+i) in-lane, and the activation output is
// directly the next step's B-fragment. slot s: gi=s>>5, hf=(s>>4)&1,
// q=(s>>2)&3, r=s&3  ->  orig gate row o = gi*32 + 8q + 4hf + r.
// ws float layout:
//   0    : Wcs [128][32]  permuted, scaled folded recurrent weights
//   4096 : Whhs[128][32]  permuted, scaled W_hh (step 0)
//   8192 : W00s[128]      permuted, scaled lp0 rank-1 column
//   8320 : W01s[128]      permuted, scaled lp1 rank-1 column
//   8448 : bg2s[128]      permuted, scaled steady-state gate bias
//   8576 : b0s [128]      permuted, scaled step-0 gate bias
__global__ void precompute_kernel(const float* __restrict__ W_se,
                                  const float* __restrict__ b_se,
                                  const float* __restrict__ W_ih,
                                  const float* __restrict__ b_ih,
                                  const float* __restrict__ W_hh,
                                  const float* __restrict__ b_hh,
                                  const float* __restrict__ W_hp,
                                  const float* __restrict__ b_hp,
                                  float* __restrict__ ws) {
    int s = threadIdx.x;
    if (s >= 128) return;
    int gi = s >> 5, hf = (s >> 4) & 1, q = (s >> 2) & 3, r = s & 3;
    int o  = gi * 32 + 8 * q + 4 * hf + r;          // original gate row
    float w0 = 0.f, w1 = 0.f, bse = 0.f;
    for (int e = 0; e < 32; ++e) {
        float wi = W_ih[o * 32 + e];
        w0  += W_se[e * 2 + 0] * wi;
        w1  += W_se[e * 2 + 1] * wi;
        bse += b_se[e] * wi;
    }
    // i,f,o rows scaled by -log2e (sigmoid via exp2); g rows by 2*log2e (tanh)
    float sc = (gi == 2) ? 2.0f * L2E : -L2E;
    for (int k = 0; k < 32; ++k) {
        float whh = W_hh[o * 32 + k];
        ws[s * 32 + k]        = sc * (whh + W_hp[k] * w0 + W_hp[32 + k] * w1);
        ws[4096 + s * 32 + k] = sc * whh;
    }
    float bg = b_ih[o] + b_hh[o] + bse;
    ws[8192 + s] = sc * w0;
    ws[8320 + s] = sc * w1;
    ws[8448 + s] = sc * (bg + b_hp[0] * w0 + b_hp[1] * w1);
    ws[8576 + s] = sc * bg;
}

__device__ __forceinline__ void split8(const float* v, half8& hi, half8& lo) {
    #pragma unroll
    for (int i = 0; i < 8; ++i) {
        _Float16 h = (_Float16)v[i];
        hi[i] = h;
        lo[i] = (_Float16)(v[i] - (float)h);
    }
}

// 4 independent waves per block, one 16-agent tile per wave. No LDS, no syncs.
__global__ __launch_bounds__(256, 3) void lstm_kernel(
        const float* __restrict__ lp,    // last_pos_rel (B,2)
        const float* __restrict__ h0g,   // hidden_state (1,B,32)
        const float* __restrict__ sp,    // start_pos (B,2)
        const float* __restrict__ Whp,   // (2,32)
        const float* __restrict__ bhp,   // (2)
        const float* __restrict__ ws,
        const int*   __restrict__ seqp,
        float* __restrict__ out, int Bn) {
    const int lane = threadIdx.x & 63;
    const int col  = lane & 15;          // agent within tile / A-row role
    const int q    = lane >> 4;
    const int tile = blockIdx.x * 4 + (threadIdx.x >> 6);
    const int base = tile * 16;
    if (base >= Bn) return;
    const int T = seqp[0];

    const float* Wcs  = ws;
    const float* Whhs = ws + 4096;
    const float* W00s = ws + 8192;
    const float* W01s = ws + 8320;
    const float* bg2s = ws + 8448;
    const float* b0s  = ws + 8576;

    // persistent A-fragments: permuted folded weights, hi/lo
    half8 wh[8], wl[8];
    #pragma unroll
    for (int t8 = 0; t8 < 8; ++t8) {
        float v[8];
        const float* p = Wcs + (size_t)(t8 * 16 + col) * 32 + 8 * q;
        #pragma unroll
        for (int i = 0; i < 8; ++i) v[i] = p[i];
        split8(v, wh[t8], wl[t8]);
    }
    // pos-head A fragment (rows 0,1 = Whp)
    half8 ph, plo;
    {
        float v[8];
        #pragma unroll
        for (int i = 0; i < 8; ++i) v[i] = (col < 2) ? Whp[col * 32 + 8 * q + i] : 0.f;
        split8(v, ph, plo);
    }
    const float pb0 = (q == 0) ? bhp[0] : 0.f;
    const float pb1 = (q == 0) ? bhp[1] : 0.f;

    // ---- step 0: gates_0^T = Whh_perm·h0^T + W0_perm⊗lp + b0 ----
    half8 b0h, b0l;                      // h0 B-fragment
    {
        float v[8];
        const float* p = h0g + (size_t)(base + col) * 32 + 8 * q;
        #pragma unroll
        for (int i = 0; i < 8; ++i) v[i] = p[i];
        split8(v, b0h, b0l);
    }
    half8 lph, lpl;                      // lp B-fragment (k=0,1 live on q==0)
    #pragma unroll
    for (int i = 0; i < 8; ++i) { lph[i] = (_Float16)0.f; lpl[i] = (_Float16)0.f; }
    if (q == 0) {
        float l0 = lp[(size_t)(base + col) * 2 + 0];
        float l1 = lp[(size_t)(base + col) * 2 + 1];
        _Float16 x0 = (_Float16)l0; lph[0] = x0; lpl[0] = (_Float16)(l0 - (float)x0);
        _Float16 x1 = (_Float16)l1; lph[1] = x1; lpl[1] = (_Float16)(l1 - (float)x1);
    }

    f32x4 accg[8];
    #pragma unroll
    for (int t8 = 0; t8 < 8; ++t8) {
        f32x4 a = *(const f32x4*)(b0s + t8 * 16 + 4 * q);
        half8 ah, al;                    // transient Whh A-fragment
        {
            float v[8];
            const float* p = Whhs + (size_t)(t8 * 16 + col) * 32 + 8 * q;
            #pragma unroll
            for (int i = 0; i < 8; ++i) v[i] = p[i];
            split8(v, ah, al);
        }
        a = MFMA(ah, b0h, a); a = MFMA(al, b0h, a); a = MFMA(ah, b0l, a);
        half8 ch, cl;                    // lp rank-2 A-fragment (k=0,1)
        #pragma unroll
        for (int i = 0; i < 8; ++i) { ch[i] = (_Float16)0.f; cl[i] = (_Float16)0.f; }
        if (q == 0) {
            float w0v = W00s[t8 * 16 + col];
            float w1v = W01s[t8 * 16 + col];
            _Float16 y0 = (_Float16)w0v; ch[0] = y0; cl[0] = (_Float16)(w0v - (float)y0);
            _Float16 y1 = (_Float16)w1v; ch[1] = y1; cl[1] = (_Float16)(w1v - (float)y1);
        }
        a = MFMA(ch, lph, a); a = MFMA(cl, lph, a); a = MFMA(ch, lpl, a);
        accg[t8] = a;
    }

    // per-lane recurrent state: agent=col, hidden j = 8q+i
    float c[8];
    #pragma unroll
    for (int i = 0; i < 8; ++i) c[i] = 0.f;
    float run0 = 0.f, run1 = 0.f;
    if (q == 0) {
        run0 = sp[(size_t)(base + col) * 2 + 0];
        run1 = sp[(size_t)(base + col) * 2 + 1];
    }

    float hn[8];
    #pragma unroll 1
    for (int n = 0; n < T; ++n) {
        // ---- activations: accg[2*gi+hf][r] = gate gi for j = 8q+4hf+r ----
        #pragma unroll
        for (int hf = 0; hf < 2; ++hf) {
            #pragma unroll
            for (int r = 0; r < 4; ++r) {
                const int i = 4 * hf + r;
                float gi = accg[0 + hf][r];   // pre-scaled by -log2e
                float gf = accg[2 + hf][r];
                float gg = accg[4 + hf][r];   // pre-scaled by 2log2e
                float go = accg[6 + hf][r];
                float ei = __builtin_amdgcn_exp2f(gi);
                float ef = __builtin_amdgcn_exp2f(gf);
                float eg = __builtin_amdgcn_exp2f(gg);
                float eo = __builtin_amdgcn_exp2f(go);
                float Di = 1.f + ei, Df = 1.f + ef, Dg = 1.f + eg, Do = 1.f + eo;
                float P  = Di * Dg;
                float R  = __builtin_amdgcn_rcpf(P * Df);
                float cn = fmaf(eg - 1.f, Df, c[i] * P) * R;
                c[i] = cn;
                float ec = __builtin_amdgcn_exp2f(cn * (2.f * L2E));
                float Rs = __builtin_amdgcn_rcpf((1.f + ec) * Do);
                hn[i] = (ec - 1.f) * Rs;
            }
        }
        // h_{n+1} is directly the next B-fragment — no LDS, no shuffles
        half8 bh, bl;
        split8(hn, bh, bl);

        // ---- pos_n^T = Whp·h^T + bhp (rows 0,1 -> q==0, reg 0,1) ----
        f32x4 ap;
        ap[0] = pb0; ap[1] = pb1; ap[2] = 0.f; ap[3] = 0.f;
        ap = MFMA(ph, bh, ap); ap = MFMA(plo, bh, ap); ap = MFMA(ph, bl, ap);

        // ---- gates_{n+1}^T = Wc_perm·h^T + bg2 ----
        if (n + 1 < T) {
            #pragma unroll
            for (int t8 = 0; t8 < 8; ++t8) {
                f32x4 a = *(const f32x4*)(bg2s + t8 * 16 + 4 * q);  // L2-hot
                a = MFMA(wh[t8], bh, a);
                a = MFMA(wl[t8], bh, a);
                a = MFMA(wh[t8], bl, a);
                accg[t8] = a;
            }
        }

        // ---- cumsum + coalesced float2 store (lanes 0..15) ----
        if (q == 0) {
            run0 += ap[0]; run1 += ap[1];
            float2 w2; w2.x = run0; w2.y = run1;
            *(float2*)(out + 2 * ((size_t)n * Bn + base + col)) = w2;
        }
    }

    // ---- final hidden state: lane holds h[agent=col][8q..8q+7] ----
    {
        float* p = out + (size_t)T * Bn * 2 + (size_t)(base + col) * 32 + 8 * q;
        float4 v0, v1;
        v0.x = hn[0]; v0.y = hn[1]; v0.z = hn[2]; v0.w = hn[3];
        v1.x = hn[4]; v1.y = hn[5]; v1.z = hn[6]; v1.w = hn[7];
        *(float4*)(p)     = v0;
        *(float4*)(p + 4) = v1;
    }
}

extern "C" void kernel_launch(void* const* d_in, const int* in_sizes, int n_in,
                              void* d_out, int out_size, void* d_ws, size_t ws_size,
                              hipStream_t stream) {
    const float* last_pos_rel = (const float*)d_in[0];
    const float* hidden_state = (const float*)d_in[1];
    const float* start_pos    = (const float*)d_in[2];
    const float* W_se         = (const float*)d_in[3];
    const float* b_se         = (const float*)d_in[4];
    const float* W_ih         = (const float*)d_in[5];
    const float* b_ih         = (const float*)d_in[6];
    const float* W_hh         = (const float*)d_in[7];
    const float* b_hh         = (const float*)d_in[8];
    const float* W_hp         = (const float*)d_in[9];
    const float* b_hp         = (const float*)d_in[10];
    const int*   seq_len      = (const int*)d_in[11];

    float* out = (float*)d_out;
    float* ws  = (float*)d_ws;

    const int Bn = in_sizes[0] / 2;

    hipLaunchKernelGGL(precompute_kernel, dim3(1), dim3(128), 0, stream,
                       W_se, b_se, W_ih, b_ih, W_hh, b_hh, W_hp, b_hp, ws);

    const int ntiles = (Bn + 15) / 16;
    const int nblk   = (ntiles + 3) / 4;
    hipLaunchKernelGGL(lstm_kernel, dim3(nblk), dim3(256), 0, stream,
                       last_pos_rel, hidden_state, start_pos, W_hp, b_hp,
                       ws, seq_len, out, Bn);
}

// Round 5
// 261.026 us; speedup vs baseline: 9.0112x; 1.2001x over previous
//
#include <hip/hip_runtime.h>

typedef _Float16 half8  __attribute__((ext_vector_type(8)));
typedef __fp16   half2v __attribute__((ext_vector_type(2)));   // cvt_pkrtz return type
typedef float    f32x4  __attribute__((ext_vector_type(4)));
typedef float    f32x2  __attribute__((ext_vector_type(2)));

#define L2E 1.44269504088896340736f
#define MFMA(a, b, c) __builtin_amdgcn_mfma_f32_16x16x32_f16((a), (b), (c), 0, 0, 0)

// Row-permuted + pre-scaled weights: D-fragment of gates^T = Wc·h^T lands
// i,f,g,o for (agent=col, j=8q+i) in-lane; activation output is directly the
// next step's B-fragment. slot s: gi=s>>5, hf=(s>>4)&1, q=(s>>2)&3, r=s&3
//   -> orig gate row o = gi*32 + 8q + 4hf + r.
// ws float layout:
//   0    : Wcs [128][32]  permuted, scaled folded recurrent weights
//   4096 : Whhs[128][32]  permuted, scaled W_hh (step 0)
//   8192 : W00s[128]      permuted, scaled lp0 rank-1 column
//   8320 : W01s[128]      permuted, scaled lp1 rank-1 column
//   8448 : bg2s[128]      permuted, scaled steady-state gate bias
//   8576 : b0s [128]      permuted, scaled step-0 gate bias
__global__ void precompute_kernel(const float* __restrict__ W_se,
                                  const float* __restrict__ b_se,
                                  const float* __restrict__ W_ih,
                                  const float* __restrict__ b_ih,
                                  const float* __restrict__ W_hh,
                                  const float* __restrict__ b_hh,
                                  const float* __restrict__ W_hp,
                                  const float* __restrict__ b_hp,
                                  float* __restrict__ ws) {
    int s = threadIdx.x;
    if (s >= 128) return;
    int gi = s >> 5, hf = (s >> 4) & 1, q = (s >> 2) & 3, r = s & 3;
    int o  = gi * 32 + 8 * q + 4 * hf + r;          // original gate row
    float w0 = 0.f, w1 = 0.f, bse = 0.f;
    for (int e = 0; e < 32; ++e) {
        float wi = W_ih[o * 32 + e];
        w0  += W_se[e * 2 + 0] * wi;
        w1  += W_se[e * 2 + 1] * wi;
        bse += b_se[e] * wi;
    }
    // i,f,o rows scaled by -log2e (sigmoid via exp2); g rows by 2*log2e (tanh)
    float sc = (gi == 2) ? 2.0f * L2E : -L2E;
    for (int k = 0; k < 32; ++k) {
        float whh = W_hh[o * 32 + k];
        ws[s * 32 + k]        = sc * (whh + W_hp[k] * w0 + W_hp[32 + k] * w1);
        ws[4096 + s * 32 + k] = sc * whh;
    }
    float bg = b_ih[o] + b_hh[o] + bse;
    ws[8192 + s] = sc * w0;
    ws[8320 + s] = sc * w1;
    ws[8448 + s] = sc * (bg + b_hp[0] * w0 + b_hp[1] * w1);
    ws[8576 + s] = sc * bg;
}

// exact hi/lo f16 split of 8 floats (pkrtz hi; lo = v - hi rounded)
__device__ __forceinline__ void split8(const float* v, half8& hi, half8& lo) {
    #pragma unroll
    for (int p = 0; p < 4; ++p) {
        half2v hp = __builtin_amdgcn_cvt_pkrtz(v[2 * p], v[2 * p + 1]);
        hi[2 * p] = hp.x; hi[2 * p + 1] = hp.y;
        float l0 = v[2 * p]     - (float)hp.x;
        float l1 = v[2 * p + 1] - (float)hp.y;
        half2v lp2 = __builtin_amdgcn_cvt_pkrtz(l0, l1);
        lo[2 * p] = lp2.x; lo[2 * p + 1] = lp2.y;
    }
}

// hi-only f16 conversion of 8 floats
__device__ __forceinline__ void cvt8(const float* v, half8& hi) {
    #pragma unroll
    for (int p = 0; p < 4; ++p) {
        half2v hp = __builtin_amdgcn_cvt_pkrtz(v[2 * p], v[2 * p + 1]);
        hi[2 * p] = hp.x; hi[2 * p + 1] = hp.y;
    }
}

// 4 independent waves per block, one 16-agent tile per wave. No LDS, no syncs.
__global__ __launch_bounds__(256, 4) void lstm_kernel(
        const float* __restrict__ lp,    // last_pos_rel (B,2)
        const float* __restrict__ h0g,   // hidden_state (1,B,32)
        const float* __restrict__ sp,    // start_pos (B,2)
        const float* __restrict__ Whp,   // (2,32)
        const float* __restrict__ bhp,   // (2)
        const float* __restrict__ ws,
        const int*   __restrict__ seqp,
        float* __restrict__ out, int Bn) {
    const int lane = threadIdx.x & 63;
    const int col  = lane & 15;          // agent within tile
    const int q    = lane >> 4;
    const int tile = blockIdx.x * 4 + (threadIdx.x >> 6);
    const int base = tile * 16;
    if (base >= Bn) return;
    const int T = seqp[0];

    const float* Wcs  = ws;
    const float* Whhs = ws + 4096;
    const float* W00s = ws + 8192;
    const float* W01s = ws + 8320;
    const float* bg2q = ws + 8448 + 4 * q;   // per-lane bias base
    const float* b0sq = ws + 8576 + 4 * q;

    // persistent A-fragments: permuted folded weights, f16 hi only
    half8 wh[8];
    #pragma unroll
    for (int t8 = 0; t8 < 8; ++t8) {
        float v[8];
        const float* p = Wcs + (size_t)(t8 * 16 + col) * 32 + 8 * q;
        #pragma unroll
        for (int i = 0; i < 8; ++i) v[i] = p[i];
        cvt8(v, wh[t8]);
    }
    // pos-head A fragment (rows 0,1 = Whp), f16 hi only
    half8 ph;
    {
        float v[8];
        #pragma unroll
        for (int i = 0; i < 8; ++i) v[i] = (col < 2) ? Whp[col * 32 + 8 * q + i] : 0.f;
        cvt8(v, ph);
    }
    const float pb0 = (q == 0) ? bhp[0] : 0.f;
    const float pb1 = (q == 0) ? bhp[1] : 0.f;

    // ---- step 0: gates_0^T = Whh_perm·h0^T + W0_perm⊗lp + b0 ----
    half8 b0h, b0l;                      // h0 B-fragment (hi/lo: h0 is fp32 data)
    {
        float v[8];
        const float* p = h0g + (size_t)(base + col) * 32 + 8 * q;
        #pragma unroll
        for (int i = 0; i < 8; ++i) v[i] = p[i];
        split8(v, b0h, b0l);
    }
    half8 lph, lpl;                      // lp B-fragment (k=0,1 live on q==0)
    #pragma unroll
    for (int i = 0; i < 8; ++i) { lph[i] = (_Float16)0.f; lpl[i] = (_Float16)0.f; }
    if (q == 0) {
        float l0 = lp[(size_t)(base + col) * 2 + 0];
        float l1 = lp[(size_t)(base + col) * 2 + 1];
        half2v x = __builtin_amdgcn_cvt_pkrtz(l0, l1);
        lph[0] = x.x; lph[1] = x.y;
        half2v y = __builtin_amdgcn_cvt_pkrtz(l0 - (float)x.x, l1 - (float)x.y);
        lpl[0] = y.x; lpl[1] = y.y;
    }

    f32x4 accg[8];
    #pragma unroll
    for (int t8 = 0; t8 < 8; ++t8) {
        f32x4 a = *(const f32x4*)(b0sq + t8 * 16);
        half8 ah;                        // transient Whh A-fragment (f16 hi)
        {
            float v[8];
            const float* p = Whhs + (size_t)(t8 * 16 + col) * 32 + 8 * q;
            #pragma unroll
            for (int i = 0; i < 8; ++i) v[i] = p[i];
            cvt8(v, ah);
        }
        a = MFMA(ah, b0h, a); a = MFMA(ah, b0l, a);
        half8 ch;                        // lp rank-2 A-fragment (k=0,1)
        #pragma unroll
        for (int i = 0; i < 8; ++i) ch[i] = (_Float16)0.f;
        if (q == 0) {
            half2v y = __builtin_amdgcn_cvt_pkrtz(W00s[t8 * 16 + col],
                                                  W01s[t8 * 16 + col]);
            ch[0] = y.x; ch[1] = y.y;
        }
        a = MFMA(ch, lph, a); a = MFMA(ch, lpl, a);
        accg[t8] = a;
    }

    // per-lane recurrent state: agent=col, hidden j = 8q+i
    f32x2 c2[4];
    #pragma unroll
    for (int i = 0; i < 4; ++i) c2[i] = (f32x2)0.f;
    float run0 = 0.f, run1 = 0.f;
    if (q == 0) {
        run0 = sp[(size_t)(base + col) * 2 + 0];
        run1 = sp[(size_t)(base + col) * 2 + 1];
    }

    float hn[8];
    #pragma unroll 1
    for (int n = 0; n < T; ++n) {
        // ---- activations (f32x2-packed glue; accg[2*gi+hf][r], j=8q+4hf+r) ----
        #pragma unroll
        for (int hf = 0; hf < 2; ++hf) {
            #pragma unroll
            for (int rp = 0; rp < 2; ++rp) {
                const int idx = 2 * hf + rp;     // c2 index
                f32x2 gI, gF, gG, gO;
                gI.x = accg[0 + hf][2 * rp]; gI.y = accg[0 + hf][2 * rp + 1];
                gF.x = accg[2 + hf][2 * rp]; gF.y = accg[2 + hf][2 * rp + 1];
                gG.x = accg[4 + hf][2 * rp]; gG.y = accg[4 + hf][2 * rp + 1];
                gO.x = accg[6 + hf][2 * rp]; gO.y = accg[6 + hf][2 * rp + 1];
                f32x2 ei, ef, eg, eo;
                ei.x = __builtin_amdgcn_exp2f(gI.x); ei.y = __builtin_amdgcn_exp2f(gI.y);
                ef.x = __builtin_amdgcn_exp2f(gF.x); ef.y = __builtin_amdgcn_exp2f(gF.y);
                eg.x = __builtin_amdgcn_exp2f(gG.x); eg.y = __builtin_amdgcn_exp2f(gG.y);
                eo.x = __builtin_amdgcn_exp2f(gO.x); eo.y = __builtin_amdgcn_exp2f(gO.y);
                f32x2 Df = ef + 1.f;
                f32x2 P  = (ei + 1.f) * (eg + 1.f);
                f32x2 PD = P * Df;
                f32x2 R;
                R.x = __builtin_amdgcn_rcpf(PD.x); R.y = __builtin_amdgcn_rcpf(PD.y);
                f32x2 cn = ((eg - 1.f) * Df + c2[idx] * P) * R;
                c2[idx] = cn;
                f32x2 arg = cn * (2.f * L2E);
                f32x2 ec;
                ec.x = __builtin_amdgcn_exp2f(arg.x); ec.y = __builtin_amdgcn_exp2f(arg.y);
                f32x2 DDo = (ec + 1.f) * (eo + 1.f);
                f32x2 Rs;
                Rs.x = __builtin_amdgcn_rcpf(DDo.x); Rs.y = __builtin_amdgcn_rcpf(DDo.y);
                f32x2 h2 = (ec - 1.f) * Rs;
                hn[4 * hf + 2 * rp]     = h2.x;
                hn[4 * hf + 2 * rp + 1] = h2.y;
            }
        }
        // h_{n+1} is directly the next B-fragment — exact hi/lo split
        half8 bh, bl;
        split8(hn, bh, bl);

        // ---- reload biases straight into accumulators (L1-hot, no deps) ----
        #pragma unroll
        for (int t8 = 0; t8 < 8; ++t8)
            accg[t8] = *(const f32x4*)(bg2q + t8 * 16);

        // ---- pos_n^T = Whp·h^T + bhp (rows 0,1 -> q==0, regs 0,1) ----
        f32x4 ap;
        ap[0] = pb0; ap[1] = pb1; ap[2] = 0.f; ap[3] = 0.f;
        ap = MFMA(ph, bh, ap); ap = MFMA(ph, bl, ap);

        // ---- gates_{n+1}^T = Wc_perm·h^T + bg2 ----
        #pragma unroll
        for (int t8 = 0; t8 < 8; ++t8) {
            f32x4 a = accg[t8];
            a = MFMA(wh[t8], bh, a);
            a = MFMA(wh[t8], bl, a);
            accg[t8] = a;
        }

        // ---- cumsum + coalesced float2 store (lanes 0..15) ----
        if (q == 0) {
            run0 += ap[0]; run1 += ap[1];
            float2 w2; w2.x = run0; w2.y = run1;
            *(float2*)(out + 2 * ((size_t)n * Bn + base + col)) = w2;
        }
    }

    // ---- final hidden state: lane holds h[agent=col][8q..8q+7] ----
    {
        float* p = out + (size_t)T * Bn * 2 + (size_t)(base + col) * 32 + 8 * q;
        float4 v0, v1;
        v0.x = hn[0]; v0.y = hn[1]; v0.z = hn[2]; v0.w = hn[3];
        v1.x = hn[4]; v1.y = hn[5]; v1.z = hn[6]; v1.w = hn[7];
        *(float4*)(p)     = v0;
        *(float4*)(p + 4) = v1;
    }
}

extern "C" void kernel_launch(void* const* d_in, const int* in_sizes, int n_in,
                              void* d_out, int out_size, void* d_ws, size_t ws_size,
                              hipStream_t stream) {
    const float* last_pos_rel = (const float*)d_in[0];
    const float* hidden_state = (const float*)d_in[1];
    const float* start_pos    = (const float*)d_in[2];
    const float* W_se         = (const float*)d_in[3];
    const float* b_se         = (const float*)d_in[4];
    const float* W_ih         = (const float*)d_in[5];
    const float* b_ih         = (const float*)d_in[6];
    const float* W_hh         = (const float*)d_in[7];
    const float* b_hh         = (const float*)d_in[8];
    const float* W_hp         = (const float*)d_in[9];
    const float* b_hp         = (const float*)d_in[10];
    const int*   seq_len      = (const int*)d_in[11];

    float* out = (float*)d_out;
    float* ws  = (float*)d_ws;

    const int Bn = in_sizes[0] / 2;

    hipLaunchKernelGGL(precompute_kernel, dim3(1), dim3(128), 0, stream,
                       W_se, b_se, W_ih, b_ih, W_hh, b_hh, W_hp, b_hp, ws);

    const int ntiles = (Bn + 15) / 16;
    const int nblk   = (ntiles + 3) / 4;
    hipLaunchKernelGGL(lstm_kernel, dim3(nblk), dim3(256), 0, stream,
                       last_pos_rel, hidden_state, start_pos, W_hp, b_hp,
                       ws, seq_len, out, Bn);
}

// Round 6
// 249.000 us; speedup vs baseline: 9.4464x; 1.0483x over previous
//
#include <hip/hip_runtime.h>

typedef _Float16 half8  __attribute__((ext_vector_type(8)));
typedef __fp16   half2v __attribute__((ext_vector_type(2)));   // cvt_pkrtz return type
typedef float    f32x4  __attribute__((ext_vector_type(4)));
typedef float    f32x2  __attribute__((ext_vector_type(2)));

#define L2E 1.44269504088896340736f
#define MFMA(a, b, c) __builtin_amdgcn_mfma_f32_16x16x32_f16((a), (b), (c), 0, 0, 0)

// Row-permuted + pre-scaled weights: D-fragment of gates^T = Wc·h^T lands
// i,f,g,o for (agent=col, j=8q+i) in-lane; activation output is directly the
// next step's B-fragment. slot s: gi=s>>5, hf=(s>>4)&1, q=(s>>2)&3, r=s&3
//   -> orig gate row o = gi*32 + 8q + 4hf + r.
// ws float layout:
//   0    : Wcs [128][32]  permuted, scaled folded recurrent weights
//   4096 : Whhs[128][32]  permuted, scaled W_hh (step 0)
//   8192 : W00s[128]      permuted, scaled lp0 rank-1 column
//   8320 : W01s[128]      permuted, scaled lp1 rank-1 column
//   8448 : bg2s[128]      permuted, scaled steady-state gate bias
//   8576 : b0s [128]      permuted, scaled step-0 gate bias
__global__ void precompute_kernel(const float* __restrict__ W_se,
                                  const float* __restrict__ b_se,
                                  const float* __restrict__ W_ih,
                                  const float* __restrict__ b_ih,
                                  const float* __restrict__ W_hh,
                                  const float* __restrict__ b_hh,
                                  const float* __restrict__ W_hp,
                                  const float* __restrict__ b_hp,
                                  float* __restrict__ ws) {
    int s = threadIdx.x;
    if (s >= 128) return;
    int gi = s >> 5, hf = (s >> 4) & 1, q = (s >> 2) & 3, r = s & 3;
    int o  = gi * 32 + 8 * q + 4 * hf + r;          // original gate row
    float w0 = 0.f, w1 = 0.f, bse = 0.f;
    for (int e = 0; e < 32; ++e) {
        float wi = W_ih[o * 32 + e];
        w0  += W_se[e * 2 + 0] * wi;
        w1  += W_se[e * 2 + 1] * wi;
        bse += b_se[e] * wi;
    }
    // i,f,o rows scaled by -log2e (sigmoid via exp2); g rows by 2*log2e (tanh)
    float sc = (gi == 2) ? 2.0f * L2E : -L2E;
    for (int k = 0; k < 32; ++k) {
        float whh = W_hh[o * 32 + k];
        ws[s * 32 + k]        = sc * (whh + W_hp[k] * w0 + W_hp[32 + k] * w1);
        ws[4096 + s * 32 + k] = sc * whh;
    }
    float bg = b_ih[o] + b_hh[o] + bse;
    ws[8192 + s] = sc * w0;
    ws[8320 + s] = sc * w1;
    ws[8448 + s] = sc * (bg + b_hp[0] * w0 + b_hp[1] * w1);
    ws[8576 + s] = sc * bg;
}

// exact hi/lo f16 split of 8 floats (pkrtz hi; lo = v - hi rounded)
__device__ __forceinline__ void split8(const float* v, half8& hi, half8& lo) {
    #pragma unroll
    for (int p = 0; p < 4; ++p) {
        half2v hp = __builtin_amdgcn_cvt_pkrtz(v[2 * p], v[2 * p + 1]);
        hi[2 * p] = hp.x; hi[2 * p + 1] = hp.y;
        float l0 = v[2 * p]     - (float)hp.x;
        float l1 = v[2 * p + 1] - (float)hp.y;
        half2v lp2 = __builtin_amdgcn_cvt_pkrtz(l0, l1);
        lo[2 * p] = lp2.x; lo[2 * p + 1] = lp2.y;
    }
}

// hi-only f16 conversion of 8 floats
__device__ __forceinline__ void cvt8(const float* v, half8& hi) {
    #pragma unroll
    for (int p = 0; p < 4; ++p) {
        half2v hp = __builtin_amdgcn_cvt_pkrtz(v[2 * p], v[2 * p + 1]);
        hi[2 * p] = hp.x; hi[2 * p + 1] = hp.y;
    }
}

// 4 independent waves per block, one 16-agent tile per wave. No LDS, no syncs.
__global__ __launch_bounds__(256, 3) void lstm_kernel(
        const float* __restrict__ lp,    // last_pos_rel (B,2)
        const float* __restrict__ h0g,   // hidden_state (1,B,32)
        const float* __restrict__ sp,    // start_pos (B,2)
        const float* __restrict__ Whp,   // (2,32)
        const float* __restrict__ bhp,   // (2)
        const float* __restrict__ ws,
        const int*   __restrict__ seqp,
        float* __restrict__ out, int Bn) {
    const int lane = threadIdx.x & 63;
    const int col  = lane & 15;          // agent within tile
    const int q    = lane >> 4;
    const int tile = blockIdx.x * 4 + (threadIdx.x >> 6);
    const int base = tile * 16;
    if (base >= Bn) return;
    const int T = seqp[0];

    const float* Wcs  = ws;
    const float* Whhs = ws + 4096;
    const float* W00s = ws + 8192;
    const float* W01s = ws + 8320;
    const float* bg2q = ws + 8448 + 4 * q;   // per-lane bias base
    const float* b0sq = ws + 8576 + 4 * q;

    // persistent A-fragments: permuted folded weights, f16 hi only
    half8 wh[8];
    #pragma unroll
    for (int t8 = 0; t8 < 8; ++t8) {
        float v[8];
        const float* p = Wcs + (size_t)(t8 * 16 + col) * 32 + 8 * q;
        #pragma unroll
        for (int i = 0; i < 8; ++i) v[i] = p[i];
        cvt8(v, wh[t8]);
    }
    // pos-head A fragment (rows 0,1 = Whp), f16 hi only
    half8 ph;
    {
        float v[8];
        #pragma unroll
        for (int i = 0; i < 8; ++i) v[i] = (col < 2) ? Whp[col * 32 + 8 * q + i] : 0.f;
        cvt8(v, ph);
    }
    const float pb0 = (q == 0) ? bhp[0] : 0.f;
    const float pb1 = (q == 0) ? bhp[1] : 0.f;

    // ---- step 0: gates_0^T = Whh_perm·h0^T + W0_perm⊗lp + b0 ----
    half8 b0h, b0l;                      // h0 B-fragment (hi/lo: h0 is fp32 data)
    {
        float v[8];
        const float* p = h0g + (size_t)(base + col) * 32 + 8 * q;
        #pragma unroll
        for (int i = 0; i < 8; ++i) v[i] = p[i];
        split8(v, b0h, b0l);
    }
    half8 lph, lpl;                      // lp B-fragment (k=0,1 live on q==0)
    #pragma unroll
    for (int i = 0; i < 8; ++i) { lph[i] = (_Float16)0.f; lpl[i] = (_Float16)0.f; }
    if (q == 0) {
        float l0 = lp[(size_t)(base + col) * 2 + 0];
        float l1 = lp[(size_t)(base + col) * 2 + 1];
        half2v x = __builtin_amdgcn_cvt_pkrtz(l0, l1);
        lph[0] = x.x; lph[1] = x.y;
        half2v y = __builtin_amdgcn_cvt_pkrtz(l0 - (float)x.x, l1 - (float)x.y);
        lpl[0] = y.x; lpl[1] = y.y;
    }

    f32x4 accg[8];
    #pragma unroll
    for (int t8 = 0; t8 < 8; ++t8) {
        f32x4 a = *(const f32x4*)(b0sq + t8 * 16);
        half8 ah;                        // transient Whh A-fragment (f16 hi)
        {
            float v[8];
            const float* p = Whhs + (size_t)(t8 * 16 + col) * 32 + 8 * q;
            #pragma unroll
            for (int i = 0; i < 8; ++i) v[i] = p[i];
            cvt8(v, ah);
        }
        a = MFMA(ah, b0h, a); a = MFMA(ah, b0l, a);
        half8 ch;                        // lp rank-2 A-fragment (k=0,1)
        #pragma unroll
        for (int i = 0; i < 8; ++i) ch[i] = (_Float16)0.f;
        if (q == 0) {
            half2v y = __builtin_amdgcn_cvt_pkrtz(W00s[t8 * 16 + col],
                                                  W01s[t8 * 16 + col]);
            ch[0] = y.x; ch[1] = y.y;
        }
        a = MFMA(ch, lph, a); a = MFMA(ch, lpl, a);
        accg[t8] = a;
    }

    // per-lane recurrent state: agent=col, hidden j = 8q+i
    f32x2 c2[4];
    #pragma unroll
    for (int i = 0; i < 4; ++i) c2[i] = (f32x2)0.f;
    float run0 = 0.f, run1 = 0.f;
    if (q == 0) {
        run0 = sp[(size_t)(base + col) * 2 + 0];
        run1 = sp[(size_t)(base + col) * 2 + 1];
    }

    float hn[8];
    #pragma unroll 1
    for (int n = 0; n < T; ++n) {
        // ---- prefetch next-step biases into temps (L1-hot; latency hides
        //      under the activation transcendentals below) ----
        f32x4 btmp[8];
        #pragma unroll
        for (int t8 = 0; t8 < 8; ++t8)
            btmp[t8] = *(const f32x4*)(bg2q + t8 * 16);

        // ---- activations (f32x2-packed glue; accg[2*gi+hf][r], j=8q+4hf+r) ----
        #pragma unroll
        for (int hf = 0; hf < 2; ++hf) {
            #pragma unroll
            for (int rp = 0; rp < 2; ++rp) {
                const int idx = 2 * hf + rp;     // c2 index
                f32x2 gI, gF, gG, gO;
                gI.x = accg[0 + hf][2 * rp]; gI.y = accg[0 + hf][2 * rp + 1];
                gF.x = accg[2 + hf][2 * rp]; gF.y = accg[2 + hf][2 * rp + 1];
                gG.x = accg[4 + hf][2 * rp]; gG.y = accg[4 + hf][2 * rp + 1];
                gO.x = accg[6 + hf][2 * rp]; gO.y = accg[6 + hf][2 * rp + 1];
                f32x2 ei, ef, eg, eo;
                ei.x = __builtin_amdgcn_exp2f(gI.x); ei.y = __builtin_amdgcn_exp2f(gI.y);
                ef.x = __builtin_amdgcn_exp2f(gF.x); ef.y = __builtin_amdgcn_exp2f(gF.y);
                eg.x = __builtin_amdgcn_exp2f(gG.x); eg.y = __builtin_amdgcn_exp2f(gG.y);
                eo.x = __builtin_amdgcn_exp2f(gO.x); eo.y = __builtin_amdgcn_exp2f(gO.y);
                f32x2 Df = ef + 1.f;
                f32x2 P  = (ei + 1.f) * (eg + 1.f);
                f32x2 PD = P * Df;
                f32x2 R;
                R.x = __builtin_amdgcn_rcpf(PD.x); R.y = __builtin_amdgcn_rcpf(PD.y);
                f32x2 cn = ((eg - 1.f) * Df + c2[idx] * P) * R;
                c2[idx] = cn;
                f32x2 arg = cn * (2.f * L2E);
                f32x2 ec;
                ec.x = __builtin_amdgcn_exp2f(arg.x); ec.y = __builtin_amdgcn_exp2f(arg.y);
                f32x2 DDo = (ec + 1.f) * (eo + 1.f);
                f32x2 Rs;
                Rs.x = __builtin_amdgcn_rcpf(DDo.x); Rs.y = __builtin_amdgcn_rcpf(DDo.y);
                f32x2 h2 = (ec - 1.f) * Rs;
                hn[4 * hf + 2 * rp]     = h2.x;
                hn[4 * hf + 2 * rp + 1] = h2.y;
            }
        }
        // h_{n+1} is directly the next B-fragment — exact hi/lo split
        half8 bh, bl;
        split8(hn, bh, bl);

        // ---- pos_n^T = Whp·h^T + bhp (rows 0,1 -> q==0, regs 0,1) ----
        f32x4 ap;
        ap[0] = pb0; ap[1] = pb1; ap[2] = 0.f; ap[3] = 0.f;
        ap = MFMA(ph, bh, ap); ap = MFMA(ph, bl, ap);

        // ---- gates_{n+1}^T = Wc_perm·h^T + bg2 ----
        #pragma unroll
        for (int t8 = 0; t8 < 8; ++t8) {
            f32x4 a = btmp[t8];
            a = MFMA(wh[t8], bh, a);
            a = MFMA(wh[t8], bl, a);
            accg[t8] = a;
        }

        // ---- cumsum + coalesced float2 store (lanes 0..15) ----
        if (q == 0) {
            run0 += ap[0]; run1 += ap[1];
            float2 w2; w2.x = run0; w2.y = run1;
            *(float2*)(out + 2 * ((size_t)n * Bn + base + col)) = w2;
        }
    }

    // ---- final hidden state: lane holds h[agent=col][8q..8q+7] ----
    {
        float* p = out + (size_t)T * Bn * 2 + (size_t)(base + col) * 32 + 8 * q;
        float4 v0, v1;
        v0.x = hn[0]; v0.y = hn[1]; v0.z = hn[2]; v0.w = hn[3];
        v1.x = hn[4]; v1.y = hn[5]; v1.z = hn[6]; v1.w = hn[7];
        *(float4*)(p)     = v0;
        *(float4*)(p + 4) = v1;
    }
}

extern "C" void kernel_launch(void* const* d_in, const int* in_sizes, int n_in,
                              void* d_out, int out_size, void* d_ws, size_t ws_size,
                              hipStream_t stream) {
    const float* last_pos_rel = (const float*)d_in[0];
    const float* hidden_state = (const float*)d_in[1];
    const float* start_pos    = (const float*)d_in[2];
    const float* W_se         = (const float*)d_in[3];
    const float* b_se         = (const float*)d_in[4];
    const float* W_ih         = (const float*)d_in[5];
    const float* b_ih         = (const float*)d_in[6];
    const float* W_hh         = (const float*)d_in[7];
    const float* b_hh         = (const float*)d_in[8];
    const float* W_hp         = (const float*)d_in[9];
    const float* b_hp         = (const float*)d_in[10];
    const int*   seq_len      = (const int*)d_in[11];

    float* out = (float*)d_out;
    float* ws  = (float*)d_ws;

    const int Bn = in_sizes[0] / 2;

    hipLaunchKernelGGL(precompute_kernel, dim3(1), dim3(128), 0, stream,
                       W_se, b_se, W_ih, b_ih, W_hh, b_hh, W_hp, b_hp, ws);

    const int ntiles = (Bn + 15) / 16;
    const int nblk   = (ntiles + 3) / 4;
    hipLaunchKernelGGL(lstm_kernel, dim3(nblk), dim3(256), 0, stream,
                       last_pos_rel, hidden_state, start_pos, W_hp, b_hp,
                       ws, seq_len, out, Bn);
}

// Round 7
// 212.102 us; speedup vs baseline: 11.0897x; 1.1740x over previous
//
#include <hip/hip_runtime.h>

typedef _Float16 half8  __attribute__((ext_vector_type(8)));
typedef __fp16   half2v __attribute__((ext_vector_type(2)));   // cvt_pkrtz return type
typedef float    f32x4  __attribute__((ext_vector_type(4)));
typedef float    f32x2  __attribute__((ext_vector_type(2)));

#define L2E 1.44269504088896340736f
#define MFMA(a, b, c) __builtin_amdgcn_mfma_f32_16x16x32_f16((a), (b), (c), 0, 0, 0)

// Row-permuted + pre-scaled weights: D-fragment of gates^T = Wc·h^T lands
// i,f,g,o for (agent=col, j=8q+i) in-lane; activation output is directly the
// next step's B-fragment. slot s: gi=s>>5, hf=(s>>4)&1, q=(s>>2)&3, r=s&3
//   -> orig gate row o = gi*32 + 8q + 4hf + r.
// ws float layout:
//   0    : Wcs [128][32]  permuted, scaled folded recurrent weights
//   4096 : Whhs[128][32]  permuted, scaled W_hh (step 0)
//   8192 : W00s[128]      permuted, scaled lp0 rank-1 column
//   8320 : W01s[128]      permuted, scaled lp1 rank-1 column
//   8448 : bg2s[128]      permuted, scaled steady-state gate bias
//   8576 : b0s [128]      permuted, scaled step-0 gate bias
__global__ void precompute_kernel(const float* __restrict__ W_se,
                                  const float* __restrict__ b_se,
                                  const float* __restrict__ W_ih,
                                  const float* __restrict__ b_ih,
                                  const float* __restrict__ W_hh,
                                  const float* __restrict__ b_hh,
                                  const float* __restrict__ W_hp,
                                  const float* __restrict__ b_hp,
                                  float* __restrict__ ws) {
    int s = threadIdx.x;
    if (s >= 128) return;
    int gi = s >> 5, hf = (s >> 4) & 1, q = (s >> 2) & 3, r = s & 3;
    int o  = gi * 32 + 8 * q + 4 * hf + r;          // original gate row
    float w0 = 0.f, w1 = 0.f, bse = 0.f;
    for (int e = 0; e < 32; ++e) {
        float wi = W_ih[o * 32 + e];
        w0  += W_se[e * 2 + 0] * wi;
        w1  += W_se[e * 2 + 1] * wi;
        bse += b_se[e] * wi;
    }
    // i,f,o rows scaled by -log2e (sigmoid via exp2); g rows by 2*log2e (tanh)
    float sc = (gi == 2) ? 2.0f * L2E : -L2E;
    for (int k = 0; k < 32; ++k) {
        float whh = W_hh[o * 32 + k];
        ws[s * 32 + k]        = sc * (whh + W_hp[k] * w0 + W_hp[32 + k] * w1);
        ws[4096 + s * 32 + k] = sc * whh;
    }
    float bg = b_ih[o] + b_hh[o] + bse;
    ws[8192 + s] = sc * w0;
    ws[8320 + s] = sc * w1;
    ws[8448 + s] = sc * (bg + b_hp[0] * w0 + b_hp[1] * w1);
    ws[8576 + s] = sc * bg;
}

// exact hi/lo f16 split of 8 floats (pkrtz hi; lo = v - hi rounded)
__device__ __forceinline__ void split8(const float* v, half8& hi, half8& lo) {
    #pragma unroll
    for (int p = 0; p < 4; ++p) {
        half2v hp = __builtin_amdgcn_cvt_pkrtz(v[2 * p], v[2 * p + 1]);
        hi[2 * p] = hp.x; hi[2 * p + 1] = hp.y;
        float l0 = v[2 * p]     - (float)hp.x;
        float l1 = v[2 * p + 1] - (float)hp.y;
        half2v lp2 = __builtin_amdgcn_cvt_pkrtz(l0, l1);
        lo[2 * p] = lp2.x; lo[2 * p + 1] = lp2.y;
    }
}

// hi-only f16 conversion of 8 floats
__device__ __forceinline__ void cvt8(const float* v, half8& hi) {
    #pragma unroll
    for (int p = 0; p < 4; ++p) {
        half2v hp = __builtin_amdgcn_cvt_pkrtz(v[2 * p], v[2 * p + 1]);
        hi[2 * p] = hp.x; hi[2 * p + 1] = hp.y;
    }
}

// 4 independent waves per block, one 16-agent tile per wave. No LDS, no syncs.
__global__ __launch_bounds__(256, 4) void lstm_kernel(
        const float* __restrict__ lp,    // last_pos_rel (B,2)
        const float* __restrict__ h0g,   // hidden_state (1,B,32)
        const float* __restrict__ sp,    // start_pos (B,2)
        const float* __restrict__ Whp,   // (2,32)
        const float* __restrict__ bhp,   // (2)
        const float* __restrict__ ws,
        const int*   __restrict__ seqp,
        float* __restrict__ out, int Bn) {
    const int lane = threadIdx.x & 63;
    const int col  = lane & 15;          // agent within tile
    const int q    = lane >> 4;
    const int tile = blockIdx.x * 4 + (threadIdx.x >> 6);
    const int base = tile * 16;
    if (base >= Bn) return;
    const int T = seqp[0];

    const float* Wcs  = ws;
    const float* Whhs = ws + 4096;
    const float* W00s = ws + 8192;
    const float* W01s = ws + 8320;
    const float* bg2q = ws + 8448 + 4 * q;   // per-lane bias base
    const float* b0sq = ws + 8576 + 4 * q;

    // persistent A-fragments: permuted folded weights, f16 hi only
    half8 wh[8];
    #pragma unroll
    for (int t8 = 0; t8 < 8; ++t8) {
        float v[8];
        const float* p = Wcs + (size_t)(t8 * 16 + col) * 32 + 8 * q;
        #pragma unroll
        for (int i = 0; i < 8; ++i) v[i] = p[i];
        cvt8(v, wh[t8]);
    }
    // pos-head A fragment (rows 0,1 = Whp), f16 hi only
    half8 ph;
    {
        float v[8];
        #pragma unroll
        for (int i = 0; i < 8; ++i) v[i] = (col < 2) ? Whp[col * 32 + 8 * q + i] : 0.f;
        cvt8(v, ph);
    }
    const float pb0 = (q == 0) ? bhp[0] : 0.f;
    const float pb1 = (q == 0) ? bhp[1] : 0.f;

    // ---- step 0: gates_0^T = Whh_perm·h0^T + W0_perm⊗lp + b0 ----
    // (one-time: full hi/lo precision for the fp32 h0 and lp inputs)
    half8 b0h, b0l;
    {
        float v[8];
        const float* p = h0g + (size_t)(base + col) * 32 + 8 * q;
        #pragma unroll
        for (int i = 0; i < 8; ++i) v[i] = p[i];
        split8(v, b0h, b0l);
    }
    half8 lph, lpl;                      // lp B-fragment (k=0,1 live on q==0)
    #pragma unroll
    for (int i = 0; i < 8; ++i) { lph[i] = (_Float16)0.f; lpl[i] = (_Float16)0.f; }
    if (q == 0) {
        float l0 = lp[(size_t)(base + col) * 2 + 0];
        float l1 = lp[(size_t)(base + col) * 2 + 1];
        half2v x = __builtin_amdgcn_cvt_pkrtz(l0, l1);
        lph[0] = x.x; lph[1] = x.y;
        half2v y = __builtin_amdgcn_cvt_pkrtz(l0 - (float)x.x, l1 - (float)x.y);
        lpl[0] = y.x; lpl[1] = y.y;
    }

    f32x4 accg[8];
    #pragma unroll
    for (int t8 = 0; t8 < 8; ++t8) {
        f32x4 a = *(const f32x4*)(b0sq + t8 * 16);
        half8 ah;                        // transient Whh A-fragment (f16 hi)
        {
            float v[8];
            const float* p = Whhs + (size_t)(t8 * 16 + col) * 32 + 8 * q;
            #pragma unroll
            for (int i = 0; i < 8; ++i) v[i] = p[i];
            cvt8(v, ah);
        }
        a = MFMA(ah, b0h, a); a = MFMA(ah, b0l, a);
        half8 ch;                        // lp rank-2 A-fragment (k=0,1)
        #pragma unroll
        for (int i = 0; i < 8; ++i) ch[i] = (_Float16)0.f;
        if (q == 0) {
            half2v y = __builtin_amdgcn_cvt_pkrtz(W00s[t8 * 16 + col],
                                                  W01s[t8 * 16 + col]);
            ch[0] = y.x; ch[1] = y.y;
        }
        a = MFMA(ch, lph, a); a = MFMA(ch, lpl, a);
        accg[t8] = a;
    }

    // per-lane recurrent state: agent=col, hidden j = 8q+i
    f32x2 c2[4];
    #pragma unroll
    for (int i = 0; i < 4; ++i) c2[i] = (f32x2)0.f;
    float run0 = 0.f, run1 = 0.f;
    if (q == 0) {
        run0 = sp[(size_t)(base + col) * 2 + 0];
        run1 = sp[(size_t)(base + col) * 2 + 1];
    }

    float hn[8];
    #pragma unroll 1
    for (int n = 0; n < T; ++n) {
        // ---- activations (f32x2-packed glue; accg[2*gi+hf][r], j=8q+4hf+r) ----
        #pragma unroll
        for (int hf = 0; hf < 2; ++hf) {
            #pragma unroll
            for (int rp = 0; rp < 2; ++rp) {
                const int idx = 2 * hf + rp;     // c2 index
                f32x2 gI, gF, gG, gO;
                gI.x = accg[0 + hf][2 * rp]; gI.y = accg[0 + hf][2 * rp + 1];
                gF.x = accg[2 + hf][2 * rp]; gF.y = accg[2 + hf][2 * rp + 1];
                gG.x = accg[4 + hf][2 * rp]; gG.y = accg[4 + hf][2 * rp + 1];
                gO.x = accg[6 + hf][2 * rp]; gO.y = accg[6 + hf][2 * rp + 1];
                f32x2 ei, ef, eg, eo;
                ei.x = __builtin_amdgcn_exp2f(gI.x); ei.y = __builtin_amdgcn_exp2f(gI.y);
                ef.x = __builtin_amdgcn_exp2f(gF.x); ef.y = __builtin_amdgcn_exp2f(gF.y);
                eg.x = __builtin_amdgcn_exp2f(gG.x); eg.y = __builtin_amdgcn_exp2f(gG.y);
                eo.x = __builtin_amdgcn_exp2f(gO.x); eo.y = __builtin_amdgcn_exp2f(gO.y);
                f32x2 Df = ef + 1.f;
                f32x2 P  = (ei + 1.f) * (eg + 1.f);
                f32x2 PD = P * Df;
                f32x2 R;
                R.x = __builtin_amdgcn_rcpf(PD.x); R.y = __builtin_amdgcn_rcpf(PD.y);
                f32x2 cn = ((eg - 1.f) * Df + c2[idx] * P) * R;
                c2[idx] = cn;
                f32x2 arg = cn * (2.f * L2E);
                f32x2 ec;
                ec.x = __builtin_amdgcn_exp2f(arg.x); ec.y = __builtin_amdgcn_exp2f(arg.y);
                f32x2 DDo = (ec + 1.f) * (eo + 1.f);
                f32x2 Rs;
                Rs.x = __builtin_amdgcn_rcpf(DDo.x); Rs.y = __builtin_amdgcn_rcpf(DDo.y);
                f32x2 h2 = (ec - 1.f) * Rs;
                hn[4 * hf + 2 * rp]     = h2.x;
                hn[4 * hf + 2 * rp + 1] = h2.y;
            }
        }
        // h_{n+1} as f16-hi only — directly the next B-fragment
        half8 bh;
        cvt8(hn, bh);

        // ---- pos_n^T = Whp·h^T + bhp (rows 0,1 -> q==0, regs 0,1) ----
        f32x4 ap;
        ap[0] = pb0; ap[1] = pb1; ap[2] = 0.f; ap[3] = 0.f;
        ap = MFMA(ph, bh, ap);

        // ---- gates_{n+1}^T = Wc_perm·h^T + bg2 (bias loaded transiently) ----
        #pragma unroll
        for (int t8 = 0; t8 < 8; ++t8) {
            f32x4 a = *(const f32x4*)(bg2q + t8 * 16);   // L1-hot, 16 B
            a = MFMA(wh[t8], bh, a);
            accg[t8] = a;
        }

        // ---- cumsum + coalesced float2 store (lanes 0..15) ----
        if (q == 0) {
            run0 += ap[0]; run1 += ap[1];
            float2 w2; w2.x = run0; w2.y = run1;
            *(float2*)(out + 2 * ((size_t)n * Bn + base + col)) = w2;
        }
    }

    // ---- final hidden state: lane holds h[agent=col][8q..8q+7] ----
    {
        float* p = out + (size_t)T * Bn * 2 + (size_t)(base + col) * 32 + 8 * q;
        float4 v0, v1;
        v0.x = hn[0]; v0.y = hn[1]; v0.z = hn[2]; v0.w = hn[3];
        v1.x = hn[4]; v1.y = hn[5]; v1.z = hn[6]; v1.w = hn[7];
        *(float4*)(p)     = v0;
        *(float4*)(p + 4) = v1;
    }
}

extern "C" void kernel_launch(void* const* d_in, const int* in_sizes, int n_in,
                              void* d_out, int out_size, void* d_ws, size_t ws_size,
                              hipStream_t stream) {
    const float* last_pos_rel = (const float*)d_in[0];
    const float* hidden_state = (const float*)d_in[1];
    const float* start_pos    = (const float*)d_in[2];
    const float* W_se         = (const float*)d_in[3];
    const float* b_se         = (const float*)d_in[4];
    const float* W_ih         = (const float*)d_in[5];
    const float* b_ih         = (const float*)d_in[6];
    const float* W_hh         = (const float*)d_in[7];
    const float* b_hh         = (const float*)d_in[8];
    const float* W_hp         = (const float*)d_in[9];
    const float* b_hp         = (const float*)d_in[10];
    const int*   seq_len      = (const int*)d_in[11];

    float* out = (float*)d_out;
    float* ws  = (float*)d_ws;

    const int Bn = in_sizes[0] / 2;

    hipLaunchKernelGGL(precompute_kernel, dim3(1), dim3(128), 0, stream,
                       W_se, b_se, W_ih, b_ih, W_hh, b_hh, W_hp, b_hp, ws);

    const int ntiles = (Bn + 15) / 16;
    const int nblk   = (ntiles + 3) / 4;
    hipLaunchKernelGGL(lstm_kernel, dim3(nblk), dim3(256), 0, stream,
                       last_pos_rel, hidden_state, start_pos, W_hp, b_hp,
                       ws, seq_len, out, Bn);
}